// Round 11
// baseline (186.265 us; speedup 1.0000x reference)
//
#include <hip/hip_runtime.h>

// LocBlock2dNT: x (64,64,64,64) f32, w (256,64,16,16,16) f32
// out (64,256,16,16) f32 = relu( einsum('ncpqf,ocpqf->nopq', patches, w) / 32 )
//
// SINGLE kernel: block = (p, q-pair, o-half), grid 256 (r9 structure).
// Cache-policy experiment: w (256 MB = L3 size, re-read every replay) keeps
// default caching; x loads and out stores are NON-TEMPORAL so they don't
// thrash w out of the Infinity Cache. w should converge to L3-resident ->
// its stream latency class drops -> per-CU request-queue occupancy drops.

typedef short bf16x8 __attribute__((ext_vector_type(8)));
typedef float f32x4  __attribute__((ext_vector_type(4)));

__device__ __forceinline__ short f2bf(float f) {
    union { float f; unsigned u; } v; v.f = f;
    return (short)((v.u + 0x7FFFu + ((v.u >> 16) & 1u)) >> 16);   // RNE
}

__device__ __forceinline__ bf16x8 pack8(f32x4 a, f32x4 b) {
    bf16x8 r;
    r[0] = f2bf(a[0]); r[1] = f2bf(a[1]); r[2] = f2bf(a[2]); r[3] = f2bf(a[3]);
    r[4] = f2bf(b[0]); r[5] = f2bf(b[1]); r[6] = f2bf(b[2]); r[7] = f2bf(b[3]);
    return r;
}

__device__ __forceinline__ void gload16(const void* g, void* l) {
    __builtin_amdgcn_global_load_lds(
        (const __attribute__((address_space(1))) void*)g,
        (__attribute__((address_space(3))) void*)l, 16, 0, 0);
}

// non-temporal variant (aux bit1 = NT on gfx94x/gfx950 cpol)
__device__ __forceinline__ void gload16nt(const void* g, void* l) {
    __builtin_amdgcn_global_load_lds(
        (const __attribute__((address_space(1))) void*)g,
        (__attribute__((address_space(3))) void*)l, 16, 0, 2);
}

__global__ __launch_bounds__(512)
void locblock_fused(const float* __restrict__ x, const float* __restrict__ w,
                    float* __restrict__ out) {
    // 3 x [ x-tile 16 KB | w-tile 32 KB ] = 144 KB
    __shared__ __align__(16) char smem[3][49152];

    // XCD swizzle: 32 consecutive logical blocks (2 full p's) per XCD ->
    // oh-sibling x reads dedup in the XCD's L2.
    const int hw = blockIdx.x;
    const int lb = (hw & 7) * 32 + (hw >> 3);        // bijective, 256 % 8 == 0
    const int p  = lb >> 4;
    const int q2 = (lb >> 1) & 7;                    // q = 2*q2 + qw
    const int oh = lb & 1;                           // o half (128 o's)

    const int tid  = (int)threadIdx.x;
    const int lane = tid & 63;
    const int wv   = tid >> 6;                       // 0..7
    const int l15  = lane & 15;
    const int kq   = lane >> 4;                      // 0..3
    const int qw   = wv & 1;                         // wave's q within pair
    const int nc   = wv >> 1;                        // wave's o-quarter (32 o)

    // ---- staging sources. x chunk u = c*8 + fr*2 + h (32-B runs);
    //      w chunk u = c*8 + h8 (128-B runs). Source idx = slot ^ (row&15). ----
    const float* xsrc[2];
#pragma unroll
    for (int j = 0; j < 2; ++j) {
        const int id = j * 512 + tid;                // 1024 chunks of 16 B
        const int n = id >> 4, s = id & 15;
        const int u = s ^ (n & 15);
        xsrc[j] = x + (size_t)n * 262144u + (size_t)(u >> 3) * 4096u
                    + (size_t)(4 * p + ((u >> 1) & 3)) * 64u
                    + (size_t)(q2 * 8 + (u & 1) * 4);
    }
    const float* wsrc[4];
#pragma unroll
    for (int j = 0; j < 4; ++j) {
        const int id = j * 512 + tid;                // 2048 chunks of 16 B
        const int ol = id >> 4, s = id & 15;
        const int u = s ^ (ol & 15);
        wsrc[j] = w + (size_t)(oh * 128 + ol) * 262144u + (size_t)(u >> 3) * 4096u
                    + (size_t)p * 256u + (size_t)(q2 * 32) + (size_t)((u & 7) * 4);
    }

    // ---- fragment LDS byte offsets ----
    int aoff[4][2], boff[2][2];
#pragma unroll
    for (int mf = 0; mf < 4; ++mf) {
        const int n = mf * 16 + l15;
        const int v1 = (kq >> 1) * 8 + (kq & 1) * 4 + qw;      // c*8 + fr*2 + h
        aoff[mf][0] = n * 256 + ((v1       ^ l15) * 16);
        aoff[mf][1] = n * 256 + (((v1 + 2) ^ l15) * 16);       // fr+1
    }
#pragma unroll
    for (int nf = 0; nf < 2; ++nf) {
        const int ol = nc * 32 + nf * 16 + l15;
        const int u1 = (kq >> 1) * 8 + qw * 4 + (kq & 1) * 2;  // c*8 + h8
        boff[nf][0] = 16384 + ol * 256 + ((u1       ^ l15) * 16);
        boff[nf][1] = 16384 + ol * 256 + (((u1 + 1) ^ l15) * 16);
    }

    f32x4 acc[4][2];
#pragma unroll
    for (int mf = 0; mf < 4; ++mf)
#pragma unroll
        for (int nf = 0; nf < 2; ++nf)
            acc[mf][nf] = (f32x4){0.f, 0.f, 0.f, 0.f};

    auto stage = [&](int t, int buf) {
        char* base = smem[buf];
        const size_t toff = (size_t)t * 8192u;       // advance 2 c's per step
#pragma unroll
        for (int j = 0; j < 2; ++j)                  // x: non-temporal
            gload16nt(xsrc[j] + toff, base + j * 8192 + wv * 1024);
#pragma unroll
        for (int j = 0; j < 4; ++j)                  // w: default (L3-keep)
            gload16(wsrc[j] + toff, base + 16384 + j * 8192 + wv * 1024);
    };

    auto compute = [&](int buf) {
        const char* Lb = smem[buf];
        bf16x8 av[4], bv[2];
#pragma unroll
        for (int mf = 0; mf < 4; ++mf)
            av[mf] = pack8(*(const f32x4*)(Lb + aoff[mf][0]),
                           *(const f32x4*)(Lb + aoff[mf][1]));
#pragma unroll
        for (int nf = 0; nf < 2; ++nf)
            bv[nf] = pack8(*(const f32x4*)(Lb + boff[nf][0]),
                           *(const f32x4*)(Lb + boff[nf][1]));
#pragma unroll
        for (int mf = 0; mf < 4; ++mf)
#pragma unroll
            for (int nf = 0; nf < 2; ++nf)
                acc[mf][nf] = __builtin_amdgcn_mfma_f32_16x16x32_bf16(
                    av[mf], bv[nf], acc[mf][nf], 0, 0, 0);
    };

    // ---- 3-deep pipeline over 32 K-steps (6 loads/thread per stage) ----
    stage(0, 0);
    stage(1, 1);
    stage(2, 2);
#pragma unroll 1
    for (int t = 0; t < 29; ++t) {
        const int buf = t % 3;
        asm volatile("s_waitcnt vmcnt(12)" ::: "memory");  // stage t landed
        __builtin_amdgcn_s_barrier();
        compute(buf);
        asm volatile("s_waitcnt lgkmcnt(0)" ::: "memory"); // reads retired
        __builtin_amdgcn_s_barrier();
        stage(t + 3, buf);
    }
    asm volatile("s_waitcnt vmcnt(12)" ::: "memory");
    __builtin_amdgcn_s_barrier();
    compute(2);                                            // t = 29
    asm volatile("s_waitcnt vmcnt(6)" ::: "memory");
    __builtin_amdgcn_s_barrier();
    compute(0);                                            // t = 30
    asm volatile("s_waitcnt vmcnt(0)" ::: "memory");
    __builtin_amdgcn_s_barrier();
    compute(1);                                            // t = 31

    // ---- epilogue: relu-scale, non-temporal scattered stores ----
    const float scale = 0.03125f;                    // 1/sqrt(16*64)
    const int pq = p * 16 + q2 * 2 + qw;
#pragma unroll
    for (int mf = 0; mf < 4; ++mf)
#pragma unroll
        for (int nf = 0; nf < 2; ++nf) {
            const int o = oh * 128 + nc * 32 + nf * 16 + l15;
            float* ob = out + (size_t)(mf * 16 + kq * 4) * 65536u
                            + (size_t)o * 256u + pq;
#pragma unroll
            for (int j = 0; j < 4; ++j)
                __builtin_nontemporal_store(
                    fmaxf(acc[mf][nf][j] * scale, 0.0f),
                    ob + (size_t)j * 65536u);
        }
}

extern "C" void kernel_launch(void* const* d_in, const int* in_sizes, int n_in,
                              void* d_out, int out_size, void* d_ws, size_t ws_size,
                              hipStream_t stream) {
    const float* x = (const float*)d_in[0];
    const float* w = (const float*)d_in[1];
    float* out = (float*)d_out;
    locblock_fused<<<dim3(256), dim3(512), 0, stream>>>(x, w, out);
}

// Round 12
// 86.405 us; speedup vs baseline: 2.1557x; 2.1557x over previous
//
#include <hip/hip_runtime.h>

// LocBlock2dNT: x (64,64,64,64) f32, w (256,64,16,16,16) f32
// out (64,256,16,16) f32 = relu( einsum('ncpqf,ocpqf->nopq', patches, w) / 32 )
//
// SINGLE kernel. block = (p, q-quad, o-quarter), grid 256, 512 thr.
//   Wave (qi, ow): GEMM 64n x 32o for q = q4*4+qi, K = 1024.
//   w read EXACTLY once (q4 x oq partitions w); x dup x4 (same-XCD L2).
//   Staging runs: x 64 B, w 256 B (XOR source swizzle keeps runs, since
//   XOR with (row&15) permutes chunks within aligned 64-B quads only).
//   2-deep global_load_lds pipeline (2 x 64 KB), counted vmcnt(8).
//   Epilogue: LDS transpose (smem overlay) -> 16-B pq-contiguous stores;
//   the 4 sibling q4-blocks (same XCD) complete each 64-B out line in L2.

typedef short bf16x8 __attribute__((ext_vector_type(8)));
typedef float f32x4  __attribute__((ext_vector_type(4)));

__device__ __forceinline__ short f2bf(float f) {
    union { float f; unsigned u; } v; v.f = f;
    return (short)((v.u + 0x7FFFu + ((v.u >> 16) & 1u)) >> 16);   // RNE
}

__device__ __forceinline__ bf16x8 pack8(f32x4 a, f32x4 b) {
    bf16x8 r;
    r[0] = f2bf(a[0]); r[1] = f2bf(a[1]); r[2] = f2bf(a[2]); r[3] = f2bf(a[3]);
    r[4] = f2bf(b[0]); r[5] = f2bf(b[1]); r[6] = f2bf(b[2]); r[7] = f2bf(b[3]);
    return r;
}

__device__ __forceinline__ void gload16(const void* g, void* l) {
    __builtin_amdgcn_global_load_lds(
        (const __attribute__((address_space(1))) void*)g,
        (__attribute__((address_space(3))) void*)l, 16, 0, 0);
}

__global__ __launch_bounds__(512)
void locblock_fused(const float* __restrict__ x, const float* __restrict__ w,
                    float* __restrict__ out) {
    // 2 bufs x [ x-tile 32 KB | w-tile 32 KB ] = 128 KB; epilogue overlays.
    __shared__ __align__(16) char smem[131072];

    // XCD swizzle: 32 consecutive logical blocks (2 full p's) per XCD.
    const int hw = blockIdx.x;
    const int lb = (hw & 7) * 32 + (hw >> 3);        // bijective, 256 % 8 == 0
    const int p  = lb >> 4;                          // 0..15
    const int q4 = (lb >> 2) & 3;                    // q-quad: q = q4*4 + qi
    const int oq = lb & 3;                           // o-quarter (64 o's)

    const int tid  = (int)threadIdx.x;
    const int lane = tid & 63;
    const int wv   = tid >> 6;                       // 0..7
    const int l15  = lane & 15;
    const int kq   = lane >> 4;                      // 0..3
    const int qiw  = wv >> 1;                        // wave's q within quad
    const int ow   = wv & 1;                         // wave's o-half (32 o)

    // ---- staging sources (t = 0; advance 8192 floats per step = 2 c's) ----
    // x: 2048 chunks/step; chunk u (per n) = c_off*16 + fr*4 + qi.
    //    LDS slot s holds source u = s ^ (n&15) (low-4-bit XOR, runs kept).
    const float* xsrc[4];
#pragma unroll
    for (int j = 0; j < 4; ++j) {
        const int id = j * 512 + tid;
        const int n = id >> 5, s = id & 31;
        const int u = s ^ (n & 15);
        xsrc[j] = x + (size_t)n * 262144u + (size_t)(u >> 4) * 4096u
                    + (size_t)(4 * p + ((u >> 2) & 3)) * 64u
                    + (size_t)(q4 * 16 + (u & 3) * 4);
    }
    // w: 2048 chunks/step; chunk u (per o) = c_off*16 + (qi*4 + kk).
    const float* wsrc[4];
#pragma unroll
    for (int j = 0; j < 4; ++j) {
        const int id = j * 512 + tid;
        const int o = id >> 5, s = id & 31;
        const int u = s ^ (o & 15);
        wsrc[j] = w + (size_t)(oq * 64 + o) * 262144u + (size_t)(u >> 4) * 4096u
                    + (size_t)p * 256u + (size_t)(q4 * 64) + (size_t)((u & 15) * 4);
    }

    // ---- fragment LDS byte offsets ----
    // A: n = mf*16+l15; k32 = kq*8+j -> c_off = kq>>1, fr = (kq&1)*2 + d,
    //    fc = j&3, qi = qiw. phys_low = ((fr*4 + qiw) ^ l15).
    int aoff[4][2], boff[2][2];
    {
        const int coff = kq >> 1, fr0 = (kq & 1) * 2;
#pragma unroll
        for (int mf = 0; mf < 4; ++mf) {
            const int n = mf * 16 + l15;
#pragma unroll
            for (int d = 0; d < 2; ++d)
                aoff[mf][d] = n * 512
                    + (coff * 16 + (((fr0 + d) * 4 + qiw) ^ l15)) * 16;
        }
        // B: o = ow*32 + nf*16 + l15; m = qiw*4 + (kq&1)*2 + e
#pragma unroll
        for (int nf = 0; nf < 2; ++nf) {
            const int o = ow * 32 + nf * 16 + l15;
#pragma unroll
            for (int e = 0; e < 2; ++e)
                boff[nf][e] = 32768 + o * 512
                    + (coff * 16 + ((qiw * 4 + (kq & 1) * 2 + e) ^ l15)) * 16;
        }
    }

    f32x4 acc[4][2];
#pragma unroll
    for (int mf = 0; mf < 4; ++mf)
#pragma unroll
        for (int nf = 0; nf < 2; ++nf)
            acc[mf][nf] = (f32x4){0.f, 0.f, 0.f, 0.f};

    auto stage = [&](int t) {
        char* base = smem + (size_t)(t & 1) * 65536u;
        const size_t toff = (size_t)t * 8192u;
#pragma unroll
        for (int j = 0; j < 4; ++j)
            gload16(xsrc[j] + toff, base + j * 8192 + tid * 16);
#pragma unroll
        for (int j = 0; j < 4; ++j)
            gload16(wsrc[j] + toff, base + 32768 + j * 8192 + tid * 16);
    };

    auto compute = [&](int t) {
        const char* Lb = smem + (size_t)(t & 1) * 65536u;
        bf16x8 av[4], bv[2];
#pragma unroll
        for (int mf = 0; mf < 4; ++mf)
            av[mf] = pack8(*(const f32x4*)(Lb + aoff[mf][0]),
                           *(const f32x4*)(Lb + aoff[mf][1]));
#pragma unroll
        for (int nf = 0; nf < 2; ++nf)
            bv[nf] = pack8(*(const f32x4*)(Lb + boff[nf][0]),
                           *(const f32x4*)(Lb + boff[nf][1]));
#pragma unroll
        for (int mf = 0; mf < 4; ++mf)
#pragma unroll
            for (int nf = 0; nf < 2; ++nf)
                acc[mf][nf] = __builtin_amdgcn_mfma_f32_16x16x32_bf16(
                    av[mf], bv[nf], acc[mf][nf], 0, 0, 0);
    };

    // ---- 2-deep pipeline over 32 K-steps (8 loads/thread per stage) ----
    stage(0);
    stage(1);
#pragma unroll 1
    for (int t = 0; t < 30; ++t) {
        asm volatile("s_waitcnt vmcnt(8)" ::: "memory");   // stage t landed
        __builtin_amdgcn_s_barrier();
        compute(t);
        asm volatile("s_waitcnt lgkmcnt(0)" ::: "memory"); // reads retired
        __builtin_amdgcn_s_barrier();
        stage(t + 2);
    }
    asm volatile("s_waitcnt vmcnt(8)" ::: "memory");
    __builtin_amdgcn_s_barrier();
    compute(30);
    asm volatile("s_waitcnt vmcnt(0)" ::: "memory");
    __builtin_amdgcn_s_barrier();
    compute(31);

    __syncthreads();                                 // smem reuse fence

    // ---- epilogue 1: acc -> T[q][o][n], o-stride 72 words (16-B aligned) ----
    float* T = (float*)smem;                         // 4*64*72*4 = 73728 B
    const float scale = 0.03125f;                    // 1/sqrt(16*64)
#pragma unroll
    for (int mf = 0; mf < 4; ++mf)
#pragma unroll
        for (int nf = 0; nf < 2; ++nf) {
            const int o  = ow * 32 + nf * 16 + l15;
            const int n0 = mf * 16 + kq * 4;         // D row = kq*4 + j
            f32x4 r;
#pragma unroll
            for (int j = 0; j < 4; ++j)
                r[j] = fmaxf(acc[mf][nf][j] * scale, 0.0f);
            *(f32x4*)(T + (size_t)(qiw * 64 + o) * 72u + n0) = r;
        }
    __syncthreads();

    // ---- epilogue 2: T -> out, 16-B pq-contiguous stores ----
#pragma unroll
    for (int i = 0; i < 8; ++i) {
        const int item = i * 512 + tid;              // 4096 = 64n x 64o
        const int n = item >> 6, o = item & 63;
        f32x4 r;
#pragma unroll
        for (int s = 0; s < 4; ++s)
            r[s] = T[(size_t)(s * 64 + o) * 72u + n];
        *(f32x4*)(out + (size_t)n * 65536u + (size_t)(oq * 64 + o) * 256u
                      + (size_t)(p * 16 + q4 * 4)) = r;
    }
}

extern "C" void kernel_launch(void* const* d_in, const int* in_sizes, int n_in,
                              void* d_out, int out_size, void* d_ws, size_t ws_size,
                              hipStream_t stream) {
    const float* x = (const float*)d_in[0];
    const float* w = (const float*)d_in[1];
    float* out = (float*)d_out;
    locblock_fused<<<dim3(256), dim3(512), 0, stream>>>(x, w, out);
}

// Round 13
// 85.483 us; speedup vs baseline: 2.1790x; 1.0108x over previous
//
#include <hip/hip_runtime.h>

// LocBlock2dNT: x (64,64,64,64) f32, w (256,64,16,16,16) f32
// out (64,256,16,16) f32 = relu( einsum('ncpqf,ocpqf->nopq', patches, w) / 32 )
//
// SINGLE kernel. block = (p, q-quad, o-quarter), grid 256, 512 thr (r12 geom).
// NEW schedule: BK = 1 c (64 K-steps), 4 x 32 KB LDS bufs, depth-3 pipeline,
//   stage issued BEFORE compute, ONE barrier per step:
//     vmcnt(8) -> s_barrier -> stage(t+3) -> compute(t)
//   Loads issue continuously; 96 KB/CU in flight during compute.
// MFMA 16x16x16 f16 (K=16 = one c), r10-verified fragment mapping.
// Epilogue: LDS-transpose (overlay) -> 16-B pq-contiguous stores (r12).

typedef float    f32x4 __attribute__((ext_vector_type(4)));
typedef _Float16 f16x4 __attribute__((ext_vector_type(4)));

__device__ __forceinline__ void gload16(const void* g, void* l) {
    __builtin_amdgcn_global_load_lds(
        (const __attribute__((address_space(1))) void*)g,
        (__attribute__((address_space(3))) void*)l, 16, 0, 0);
}

__device__ __forceinline__ f16x4 cvt4(f32x4 v) {
    f16x4 r;
    r[0] = (_Float16)v[0]; r[1] = (_Float16)v[1];
    r[2] = (_Float16)v[2]; r[3] = (_Float16)v[3];
    return r;
}

__global__ __launch_bounds__(512)
void locblock_fused(const float* __restrict__ x, const float* __restrict__ w,
                    float* __restrict__ out) {
    // 4 bufs x [ x 16 KB | w 16 KB ] = 128 KB; epilogue overlays (72 KB).
    __shared__ __align__(16) char smem[131072];

    // XCD swizzle: 32 consecutive logical blocks (2 full p's) per XCD.
    const int hw = blockIdx.x;
    const int lb = (hw & 7) * 32 + (hw >> 3);        // bijective, 256 % 8 == 0
    const int p  = lb >> 4;                          // 0..15
    const int q4 = (lb >> 2) & 3;                    // q = q4*4 + qi
    const int oq = lb & 3;                           // o-quarter (64 o's)

    const int tid  = (int)threadIdx.x;
    const int lane = tid & 63;
    const int l15  = lane & 15;
    const int kq   = lane >> 4;                      // 0..3
    const int wv   = tid >> 6;                       // 0..7
    const int qiw  = wv >> 1;                        // wave's q within quad
    const int ow   = wv & 1;                         // wave's o-half (32 o)

    // ---- staging sources (advance 4096 floats = 1 c per step) ----
    // x: 1024 chunks/step; per n, chunk u = fr*4 + qi (64-B runs per fr).
    //    LDS slot s holds source u = s ^ (n&15).
    const float* xsrc[2];
#pragma unroll
    for (int j = 0; j < 2; ++j) {
        const int id = j * 512 + tid;
        const int n = id >> 4, s = id & 15;
        const int u = s ^ (n & 15);
        xsrc[j] = x + (size_t)n * 262144u
                    + (size_t)(4 * p + (u >> 2)) * 64u
                    + (size_t)(q4 * 16 + (u & 3) * 4);
    }
    // w: 1024 chunks/step; per o, chunk u = qi*4 + kk (256-B runs per (o,c)).
    const float* wsrc[2];
#pragma unroll
    for (int j = 0; j < 2; ++j) {
        const int id = j * 512 + tid;
        const int o = id >> 4, s = id & 15;
        const int u = s ^ (o & 15);
        wsrc[j] = w + (size_t)(oq * 64 + o) * 262144u
                    + (size_t)p * 256u + (size_t)(q4 * 64)
                    + (size_t)((u >> 2) * 16 + (u & 3) * 4);
    }

    // ---- fragment LDS byte offsets (within a 32-KB buf) ----
    // A: row n = mf*16+l15, k16 = kq*4+j -> (fr=kq, fc=j, qi=qiw):
    //    chunk u = kq*4 + qiw, stored at u ^ l15.
    // B: row o = ow*32+nf*16+l15, chunk u = qiw*4 + kq, stored at u ^ l15.
    int aoff[4], boff[2];
#pragma unroll
    for (int mf = 0; mf < 4; ++mf)
        aoff[mf] = (mf * 16 + l15) * 256 + (((kq * 4 + qiw) ^ l15) * 16);
#pragma unroll
    for (int nf = 0; nf < 2; ++nf)
        boff[nf] = 16384 + (ow * 32 + nf * 16 + l15) * 256
                 + (((qiw * 4 + kq) ^ l15) * 16);

    f32x4 acc[4][2];
#pragma unroll
    for (int mf = 0; mf < 4; ++mf)
#pragma unroll
        for (int nf = 0; nf < 2; ++nf)
            acc[mf][nf] = (f32x4){0.f, 0.f, 0.f, 0.f};

    auto stage = [&](int c) {
        char* base = smem + (size_t)(c & 3) * 32768u;
        const size_t coff = (size_t)c * 4096u;
#pragma unroll
        for (int j = 0; j < 2; ++j)
            gload16(xsrc[j] + coff, base + j * 8192 + tid * 16);
#pragma unroll
        for (int j = 0; j < 2; ++j)
            gload16(wsrc[j] + coff, base + 16384 + j * 8192 + tid * 16);
    };

    auto compute = [&](int c) {
        const char* Lb = smem + (size_t)(c & 3) * 32768u;
        f16x4 av[4], bv[2];
#pragma unroll
        for (int mf = 0; mf < 4; ++mf)
            av[mf] = cvt4(*(const f32x4*)(Lb + aoff[mf]));
#pragma unroll
        for (int nf = 0; nf < 2; ++nf)
            bv[nf] = cvt4(*(const f32x4*)(Lb + boff[nf]));
#pragma unroll
        for (int mf = 0; mf < 4; ++mf)
#pragma unroll
            for (int nf = 0; nf < 2; ++nf)
                acc[mf][nf] = __builtin_amdgcn_mfma_f32_16x16x16f16(
                    av[mf], bv[nf], acc[mf][nf], 0, 0, 0);
    };

    // ---- depth-3, issue-early, ONE barrier per step, 64 c-steps ----
    stage(0);
    stage(1);
    stage(2);
#pragma unroll 1
    for (int t = 0; t < 61; ++t) {
        asm volatile("s_waitcnt vmcnt(8)" ::: "memory");   // own stage-t done
        __builtin_amdgcn_s_barrier();                      // => everyone's done
        stage(t + 3);                                      // buf (t+3)&3 != t&3
        compute(t);
    }
    asm volatile("s_waitcnt vmcnt(8)" ::: "memory");
    __builtin_amdgcn_s_barrier();
    compute(61);
    asm volatile("s_waitcnt vmcnt(4)" ::: "memory");
    __builtin_amdgcn_s_barrier();
    compute(62);
    asm volatile("s_waitcnt vmcnt(0)" ::: "memory");
    __builtin_amdgcn_s_barrier();
    compute(63);

    __syncthreads();                                 // smem reuse fence

    // ---- epilogue 1: acc -> T[q][o][n], o-stride 72 words ----
    float* T = (float*)smem;                         // 4*64*72*4 = 73728 B
    const float scale = 0.03125f;                    // 1/sqrt(16*64)
#pragma unroll
    for (int mf = 0; mf < 4; ++mf)
#pragma unroll
        for (int nf = 0; nf < 2; ++nf) {
            const int o  = ow * 32 + nf * 16 + l15;
            const int n0 = mf * 16 + kq * 4;         // D row = kq*4 + j
            f32x4 r;
#pragma unroll
            for (int j = 0; j < 4; ++j)
                r[j] = fmaxf(acc[mf][nf][j] * scale, 0.0f);
            *(f32x4*)(T + (size_t)(qiw * 64 + o) * 72u + n0) = r;
        }
    __syncthreads();

    // ---- epilogue 2: T -> out, 16-B pq-contiguous stores ----
#pragma unroll
    for (int i = 0; i < 8; ++i) {
        const int item = i * 512 + tid;              // 4096 = 64n x 64o
        const int n = item >> 6, o = item & 63;
        f32x4 r;
#pragma unroll
        for (int s = 0; s < 4; ++s)
            r[s] = T[(size_t)(s * 64 + o) * 72u + n];
        *(f32x4*)(out + (size_t)n * 65536u + (size_t)(oq * 64 + o) * 256u
                      + (size_t)(p * 16 + q4 * 4)) = r;
    }
}

extern "C" void kernel_launch(void* const* d_in, const int* in_sizes, int n_in,
                              void* d_out, int out_size, void* d_ws, size_t ws_size,
                              hipStream_t stream) {
    const float* x = (const float*)d_in[0];
    const float* w = (const float*)d_in[1];
    float* out = (float*)d_out;
    locblock_fused<<<dim3(256), dim3(512), 0, stream>>>(x, w, out);
}